// Round 14
// baseline (210.854 us; speedup 1.0000x reference)
//
#include <hip/hip_runtime.h>

#define NB 16
#define LT 4096
#define ND 512
#define MBINS 1024
#define LMBDA 0.1f
#define FWD_THREADS 1024

__device__ __forceinline__ float2 cmulf(float2 a, float2 b) {
    return make_float2(a.x * b.x - a.y * b.y, a.x * b.y + a.y * b.x);
}
__device__ __forceinline__ float2 caddf(float2 a, float2 b) { return make_float2(a.x + b.x, a.y + b.y); }
__device__ __forceinline__ float2 csubf(float2 a, float2 b) { return make_float2(a.x - b.x, a.y - b.y); }

// base-4 digit reversal of a 12-bit index (inv kernel)
__device__ __forceinline__ int rev4_12(int t) {
    unsigned r = __brev((unsigned)t) >> 20;
    return (int)(((r & 0x555u) << 1) | ((r >> 1) & 0x555u));
}

// XOR-swizzled LDS index. Key = rank-3 GF2 hash of bits 6-11 folded into idx bits 1-3:
// keeps dense runs at the bank floor AND spreads the combine's digit-reversed reads
// (which have idx mod 64 nearly constant across a wave) over 16 bank-pairs. Bijective.
__device__ __forceinline__ int zi(int idx) {
    int h = (idx >> 6) ^ (idx >> 9);
    return idx ^ ((h & 7) << 1);
}

// Slot row of bin k for a 2048-pt DIF FFT with stage radices 4,4,4,4,4,2:
// k = q0 +4q1+16q2+64q3+256q4+1024q5  ->  row = 512q0+128q1+32q2+8q3+2q4+q5.
__device__ __forceinline__ int arow(int k) {
    return ((k & 3) << 9) | (((k >> 2) & 3) << 7) | (((k >> 4) & 3) << 5)
         | (((k >> 6) & 3) << 3) | (((k >> 8) & 3) << 1) | ((k >> 10) & 1);
}

// ws layout: float [4][NB][MBINS] : 0 -> sum|Qa|^2, 1 -> sum|Qb|^2, 2 -> Re C, 3 -> Im C
// where C = sum_d conj(Qa)*Qb.

// Forward: block = (batch, 2 consecutive d), 1024 threads, SINGLE pass (no t2 rounds).
// 4096-pt FFT = even/odd split: two 2048-pt FFTs (E rows 0..2047, O rows 2048..4095;
// 2 d-cols, real-pack a+ib). Fused load+radix-4(m=512), 4 LDS radix-4 stages, radix-2,
// then combine X[k]=E[k]+W^k O[k], X[4096-k]=E[mk]+conj(W^k) O[mk] read straight from
// LDS -- NO cross-round accumulators (R6/R8/R9's spill killer), 7 barriers total
// (R11 had ~28; R13 proved barriers not conflicts are the binding constraint).
__global__ __launch_bounds__(FWD_THREADS)
void cte_fwd_kernel(const float* __restrict__ A, const float* __restrict__ Bp,
                    float* __restrict__ ws) {
    __shared__ float2 z[8192];         // [fft E/O][2048 rows][2 cols], via zi(); 64 KB
    __shared__ float2 tw[512];         // tw[e] = exp(-2*pi*i*e/2048); 4 KB

    const int tid = threadIdx.x;
    // XCD swizzle: 8 chunks sharing each 64B line -> logical-consecutive -> same XCD,
    // co-resident -> L2 dedups the 8B-granular row reads (HBM ~1x). 4096 % 8 == 0.
    const int logical = (blockIdx.x & 7) * (gridDim.x >> 3) + (blockIdx.x >> 3);
    const int bb    = logical >> 8;           // 16 batches
    const int chunk = logical & 255;          // 256 d-chunks of 2
    const int d0    = chunk * 2;

    // ---- issue global loads first (latency hides under tw init + barrier) ----
    const int n     = tid & 511;      // stage-1 butterfly row within the 2048-FFT
    const int which = tid >> 9;       // 0 = E (even samples), 1 = O (odd samples)
    float2 A4[4], B4[4];
#pragma unroll
    for (int i = 0; i < 4; ++i) {
        size_t off = ((size_t)(bb * LT + 2 * (n + 512 * i) + which)) * ND + d0;
        A4[i] = *(const float2*)(A + off);
        B4[i] = *(const float2*)(Bp + off);
    }

    if (tid < 512) {
        float s, c;
        sincosf(-6.283185307179586f * (float)tid * (1.0f / 2048.0f), &s, &c);
        tw[tid] = make_float2(c, s);
    }
    __syncthreads();   // tw ready

    // ---- fused radix-4 stage m=512 (in registers), swizzled writes ----
    {
        float2 w1 = tw[n];
        float2 w2 = cmulf(w1, w1);
        float2 w3 = cmulf(w2, w1);
        const int base = which * 4096;     // idx base of this FFT half
#pragma unroll
        for (int c = 0; c < 2; ++c) {
            float2 x0 = c ? make_float2(A4[0].y, B4[0].y) : make_float2(A4[0].x, B4[0].x);
            float2 x1 = c ? make_float2(A4[1].y, B4[1].y) : make_float2(A4[1].x, B4[1].x);
            float2 x2 = c ? make_float2(A4[2].y, B4[2].y) : make_float2(A4[2].x, B4[2].x);
            float2 x3 = c ? make_float2(A4[3].y, B4[3].y) : make_float2(A4[3].x, B4[3].x);
            float2 t0  = caddf(x0, x2), t1v = csubf(x0, x2);
            float2 t2v = caddf(x1, x3), t3  = csubf(x1, x3);
            int ib = base + 2 * n + c;
            z[zi(ib)]        = caddf(t0, t2v);
            z[zi(ib + 1024)] = cmulf(make_float2(t1v.x + t3.y, t1v.y - t3.x), w1); // (t1-i*t3)w1
            z[zi(ib + 2048)] = cmulf(csubf(t0, t2v), w2);
            z[zi(ib + 3072)] = cmulf(make_float2(t1v.x - t3.y, t1v.y + t3.x), w3); // (t1+i*t3)w3
        }
    }
    __syncthreads();

    // ---- radix-4 stages m = 128, 32, 8, 2 (both FFTs x 2 cols) ----
#pragma unroll
    for (int st = 0; st < 4; ++st) {
        const int lgm  = 7 - 2 * st;      // 7,5,3,1
        const int m    = 1 << lgm;
        const int step = 512 >> lgm;      // 2048/(4m)
#pragma unroll
        for (int r2 = 0; r2 < 2; ++r2) {
            int u   = r2 * FWD_THREADS + tid;  // 2048 items = 2 fft x 512 bf x 2 col
            int c   = u & 1;
            int bf  = (u >> 1) & 511;
            int fft = u >> 10;
            int j   = bf & (m - 1);
            int i0  = ((bf >> lgm) << (lgm + 2)) + j;
            int ib  = fft * 4096 + c;
            int ix0 = zi(ib + 2 * i0);
            int ix1 = zi(ib + 2 * (i0 + m));
            int ix2 = zi(ib + 2 * (i0 + 2 * m));
            int ix3 = zi(ib + 2 * (i0 + 3 * m));
            float2 a0 = z[ix0], a1 = z[ix1], a2 = z[ix2], a3 = z[ix3];
            float2 t0  = caddf(a0, a2), t1v = csubf(a0, a2);
            float2 t2v = caddf(a1, a3), t3  = csubf(a1, a3);
            float2 w1 = tw[j * step];
            float2 w2 = cmulf(w1, w1);
            float2 w3 = cmulf(w2, w1);
            z[ix0] = caddf(t0, t2v);
            z[ix1] = cmulf(make_float2(t1v.x + t3.y, t1v.y - t3.x), w1);
            z[ix2] = cmulf(csubf(t0, t2v), w2);
            z[ix3] = cmulf(make_float2(t1v.x - t3.y, t1v.y + t3.x), w3);
        }
        __syncthreads();
    }

    // ---- radix-2 stage (m=1): pairs (2pr, 2pr+1), no twiddle ----
#pragma unroll
    for (int r2 = 0; r2 < 4; ++r2) {
        int u   = r2 * FWD_THREADS + tid;  // 4096 items = 2 fft x 1024 pairs x 2 col
        int c   = u & 1;
        int pr  = (u >> 1) & 1023;
        int fft = u >> 11;
        int ia  = zi(fft * 4096 + 4 * pr + c);
        int ib2 = zi(fft * 4096 + 4 * pr + 2 + c);
        float2 a = z[ia], b = z[ib2];
        z[ia]  = caddf(a, b);
        z[ib2] = csubf(a, b);
    }
    __syncthreads();

    // ---- combine + unpack + products + d-reduce + atomic flush (2 bins/thread) ----
    const int dl = tid & 1;
    const int g  = tid >> 1;          // k-group 0..511
    float2 w;
    {
        float s, c;
        sincosf(-1.5339807878856412e-03f * (float)g, &s, &c);   // -2pi/4096 * g
        w = make_float2(c, s);
    }
    const float2 wstep = make_float2(0.707106781186547524f, -0.707106781186547524f); // W4096^512
#pragma unroll
    for (int jj = 0; jj < 2; ++jj) {
        int k  = g + 512 * jj;
        int mk = (2048 - k) & 2047;
        int ak = arow(k), am = arow(mk);
        float2 Ek = z[zi(2 * ak + dl)];
        float2 Ok = z[zi(4096 + 2 * ak + dl)];
        float2 Em = z[zi(2 * am + dl)];
        float2 Om = z[zi(4096 + 2 * am + dl)];
        float2 X1 = caddf(Ek, cmulf(w, Ok));                    // X[k]
        float2 Z4 = make_float2(Em.x + w.x * Om.x + w.y * Om.y, // X[4096-k] = Em+conj(w)Om
                                Em.y + w.x * Om.y - w.y * Om.x);
        float Ar = 0.5f * (X1.x + Z4.x);
        float Ai = 0.5f * (X1.y - Z4.y);
        float Br = 0.5f * (X1.y + Z4.y);
        float Bi = 0.5f * (Z4.x - X1.x);
        float da = Ar * Ar + Ai * Ai;
        float db = Br * Br + Bi * Bi;
        float cr = Ar * Br + Ai * Bi;
        float ci = Ar * Bi - Ai * Br;
        da += __shfl_xor(da, 1);
        db += __shfl_xor(db, 1);
        cr += __shfl_xor(cr, 1);
        ci += __shfl_xor(ci, 1);
        if (dl == 0) {
            atomicAdd(&ws[0 * NB * MBINS + bb * MBINS + k], da);
            atomicAdd(&ws[1 * NB * MBINS + bb * MBINS + k], db);
            atomicAdd(&ws[2 * NB * MBINS + bb * MBINS + k], cr);
            atomicAdd(&ws[3 * NB * MBINS + bb * MBINS + k], ci);
        }
        w = cmulf(w, wstep);
    }
}

// Inverse: block = (b, dir). S = C/den (dir 0) or conj(C)/den (dir 1), padded to 4096,
// radix-4 IFFT (conj twiddles, digit-reversed output indexing), real part.
__global__ __launch_bounds__(512)
void cte_inv_kernel(const float* __restrict__ ws, float* __restrict__ out) {
    __shared__ float2 zz[4096];       // 32 KB
    __shared__ float2 tw[1024];       // tw[e] = exp(+2*pi*i*e/4096)
    const int tid = threadIdx.x;
    const int bb  = blockIdx.x >> 1;
    const int dir = blockIdx.x & 1;

    for (int i = tid; i < 1024; i += 512) {
        float s, c;
        sincosf(6.283185307179586f * (float)i * (1.0f / 4096.0f), &s, &c);
        tw[i] = make_float2(c, s);
    }
    for (int i = tid; i < 4096; i += 512) {
        float2 v = make_float2(0.f, 0.f);
        if (i < MBINS) {
            float den = ws[(dir ? 1 : 0) * NB * MBINS + bb * MBINS + i] + LMBDA;
            float cr  = ws[2 * NB * MBINS + bb * MBINS + i];
            float ci  = ws[3 * NB * MBINS + bb * MBINS + i];
            if (dir) ci = -ci;
            v = make_float2(cr / den, ci / den);
        }
        zz[i] = v;
    }
    __syncthreads();

#pragma unroll
    for (int st = 0; st < 6; ++st) {
        const int lgm  = 10 - 2 * st;     // m = 1024,256,64,16,4,1
        const int m    = 1 << lgm;
        const int step = 1024 >> lgm;     // 4096/(4m)
#pragma unroll
        for (int r = 0; r < 2; ++r) {
            int bf = r * 512 + tid;       // butterfly id [0,1024)
            int j  = bf & (m - 1);
            int i0 = ((bf >> lgm) << (lgm + 2)) + j;
            float2 a0 = zz[i0], a1 = zz[i0 + m], a2 = zz[i0 + 2 * m], a3 = zz[i0 + 3 * m];
            float2 t0  = caddf(a0, a2), t1v = csubf(a0, a2);
            float2 t2v = caddf(a1, a3), t3  = csubf(a1, a3);
            float2 y0 = caddf(t0, t2v);
            float2 y2 = csubf(t0, t2v);
            float2 y1 = make_float2(t1v.x - t3.y, t1v.y + t3.x);   // t1 + i*t3 (inverse)
            float2 y3 = make_float2(t1v.x + t3.y, t1v.y - t3.x);   // t1 - i*t3
            if (m > 1) {
                float2 w1 = tw[j * step];
                float2 w2 = cmulf(w1, w1);
                float2 w3 = cmulf(w2, w1);
                y1 = cmulf(y1, w1);
                y2 = cmulf(y2, w2);
                y3 = cmulf(y3, w3);
            }
            zz[i0] = y0; zz[i0 + m] = y1; zz[i0 + 2 * m] = y2; zz[i0 + 3 * m] = y3;
        }
        __syncthreads();
    }

    const float scale = 1.0f / 4096.0f;
    for (int t = tid; t < 4096; t += 512) {
        int rt = rev4_12(t);              // R[t] sits at digit-reversed slot
        float val = zz[rt].x * scale;
        int col = (dir == 0) ? (4095 - t) : (4096 + t);
        out[(size_t)bb * 8192 + col] = val;
    }
}

extern "C" void kernel_launch(void* const* d_in, const int* in_sizes, int n_in,
                              void* d_out, int out_size, void* d_ws, size_t ws_size,
                              hipStream_t stream) {
    const float* a = (const float*)d_in[0];
    const float* b = (const float*)d_in[1];
    // d_in[2] (offsets) only determines shapes; numerically unused.
    float* out = (float*)d_out;
    float* ws  = (float*)d_ws;

    hipMemsetAsync(d_ws, 0, 4 * NB * MBINS * sizeof(float), stream);
    cte_fwd_kernel<<<dim3(NB * (ND / 2)), dim3(FWD_THREADS), 0, stream>>>(a, b, ws);
    cte_inv_kernel<<<dim3(NB * 2), dim3(512), 0, stream>>>(ws, out);
}